// Round 1
// baseline (485.228 us; speedup 1.0000x reference)
//
#include <hip/hip_runtime.h>
#include <hip/hip_bf16.h>

// ---------------------------------------------------------------------------
// MHSelfAttention: out = softmax((X Wq)(X Wk)^T / sqrt(1024)) (X Wv), 16 heads
// X: [4,2048,1024] fp32, W: [1024,3072] fp32, out: [4,2048,1024] fp32
// Strategy: cast to bf16, MFMA GEMMs (fp32 accumulate), fp32 online softmax.
// ---------------------------------------------------------------------------

typedef __attribute__((ext_vector_type(8))) __bf16 bf16x8;
typedef __attribute__((ext_vector_type(8))) unsigned short u16x8;
typedef __attribute__((ext_vector_type(4))) float f32x4;

#define B_  4
#define S_  2048
#define H_  1024
#define NH_ 16
#define HD_ 64
#define N3_ 3072
#define M_  (B_*S_)   // 8192

static __device__ __forceinline__ unsigned short f2bf(float f) {
  __bf16 h = (__bf16)f;                 // fptrunc, round-to-nearest-even
  return __builtin_bit_cast(unsigned short, h);
}

// ---- kernel 1: embeddings fp32 -> bf16 ------------------------------------
__global__ __launch_bounds__(256) void cvt_emb_kernel(
    const float* __restrict__ in, unsigned short* __restrict__ out, int n4) {
  int i = blockIdx.x * blockDim.x + threadIdx.x;
  int stride = gridDim.x * blockDim.x;
  const float4* in4 = (const float4*)in;
  for (; i < n4; i += stride) {
    float4 v = in4[i];
    ushort4 o;
    o.x = f2bf(v.x); o.y = f2bf(v.y); o.z = f2bf(v.z); o.w = f2bf(v.w);
    ((ushort4*)out)[i] = o;
  }
}

// ---- kernel 2: w_qkv fp32 [1024][3072] -> bf16 transposed [3072][1024] ----
__global__ __launch_bounds__(256) void cvt_w_kernel(
    const float* __restrict__ in, unsigned short* __restrict__ out) {
  int i = blockIdx.x * blockDim.x + threadIdx.x;
  int stride = gridDim.x * blockDim.x;
  for (; i < H_ * N3_; i += stride) {
    int k = i / N3_, n = i - k * N3_;
    out[n * H_ + k] = f2bf(in[i]);     // reads coalesced; writes L2-absorbed
  }
}

// ---- kernel 3: QKV GEMM: C[8192][3072] = A[8192][1024] * BT[3072][1024]^T -
// 128x128 tile, BK=64, 4 waves (2x2), each wave 64x64 = 4x4 MFMA 16x16x32.
// LDS rows are 128B; XOR-swizzle byte_in_row ^ ((row&7)<<4) on write+read.
__global__ __launch_bounds__(256) void qkv_gemm_kernel(
    const unsigned short* __restrict__ A,
    const unsigned short* __restrict__ BT,
    unsigned short* __restrict__ C) {
  __shared__ __align__(16) unsigned short a_lds[128 * 64];
  __shared__ __align__(16) unsigned short b_lds[128 * 64];
  const int t = threadIdx.x;
  const int lane = t & 63;
  const int w = t >> 6;
  const int wm = w >> 1, wn = w & 1;
  const int m0 = blockIdx.y * 128;
  const int n0 = blockIdx.x * 128;
  const int lr = lane & 15;   // frag row (A: m, B: n) / D col
  const int lh = lane >> 4;   // k-chunk selector / D row group

  f32x4 acc[4][4];
  for (int i = 0; i < 4; i++)
    for (int j = 0; j < 4; j++)
      for (int r = 0; r < 4; r++) acc[i][j][r] = 0.f;

  for (int kt = 0; kt < 16; ++kt) {
    __syncthreads();
#pragma unroll
    for (int r = 0; r < 4; ++r) {                 // stage 16KB A + 16KB B
      int idx = r * 256 + t;
      int row = idx >> 3, ch = idx & 7;
      int sw = (ch * 16) ^ ((row & 7) << 4);
      u16x8 av = *(const u16x8*)(A + (size_t)(m0 + row) * H_ + kt * 64 + ch * 8);
      *(u16x8*)((char*)a_lds + row * 128 + sw) = av;
      u16x8 bv = *(const u16x8*)(BT + (size_t)(n0 + row) * H_ + kt * 64 + ch * 8);
      *(u16x8*)((char*)b_lds + row * 128 + sw) = bv;
    }
    __syncthreads();
#pragma unroll
    for (int kb = 0; kb < 2; ++kb) {
      bf16x8 af[4], bfr[4];
#pragma unroll
      for (int mi = 0; mi < 4; mi++) {
        int row = wm * 64 + mi * 16 + lr;
        int off = (kb * 64 + lh * 16) ^ ((row & 7) << 4);
        af[mi] = *(const bf16x8*)((char*)a_lds + row * 128 + off);
      }
#pragma unroll
      for (int ni = 0; ni < 4; ni++) {
        int row = wn * 64 + ni * 16 + lr;
        int off = (kb * 64 + lh * 16) ^ ((row & 7) << 4);
        bfr[ni] = *(const bf16x8*)((char*)b_lds + row * 128 + off);
      }
#pragma unroll
      for (int mi = 0; mi < 4; mi++)
#pragma unroll
        for (int ni = 0; ni < 4; ni++)
          acc[mi][ni] = __builtin_amdgcn_mfma_f32_16x16x32_bf16(
              af[mi], bfr[ni], acc[mi][ni], 0, 0, 0);
    }
  }
#pragma unroll
  for (int mi = 0; mi < 4; mi++)
#pragma unroll
    for (int ni = 0; ni < 4; ni++)
#pragma unroll
      for (int rg = 0; rg < 4; rg++) {
        int row = m0 + wm * 64 + mi * 16 + lh * 4 + rg;
        int col = n0 + wn * 64 + ni * 16 + lr;
        C[(size_t)row * N3_ + col] = f2bf(acc[mi][ni][rg]);
      }
}

// ---- kernel 4: flash attention ---------------------------------------------
// grid (qtile=32, head=16, batch=4), 256 thr. Each wave owns 16 q-rows.
// K-tile [64][64] and V^T-tile [64][64] staged in swizzled LDS per iteration.
__global__ __launch_bounds__(256) void attn_kernel(
    const unsigned short* __restrict__ QKV, float* __restrict__ out) {
  __shared__ __align__(16) unsigned short k_lds[64 * 64];
  __shared__ __align__(16) unsigned short vt_lds[64 * 64];
  __shared__ __align__(16) unsigned short p_lds[4][16 * 64];

  const int t = threadIdx.x;
  const int lane = t & 63;
  const int w = t >> 6;
  const int lr = lane & 15, lh = lane >> 4;
  const int qt = blockIdx.x;
  const int h = blockIdx.y;
  const int b = blockIdx.z;
  const int qbase = qt * 64 + w * 16;
  const float scale = 0.03125f;  // 1/sqrt(1024)

  // Q fragments live in registers for the whole kernel
  bf16x8 qf[2];
  {
    const unsigned short* qp = QKV + (size_t)(b * S_ + qbase + lr) * N3_ + h * HD_;
    qf[0] = *(const bf16x8*)(qp + lh * 8);
    qf[1] = *(const bf16x8*)(qp + 32 + lh * 8);
  }

  f32x4 o[4];
  for (int i = 0; i < 4; i++)
    for (int r = 0; r < 4; r++) o[i][r] = 0.f;
  float mrun[4], lsum[4];
  for (int i = 0; i < 4; i++) { mrun[i] = -1e30f; lsum[i] = 0.f; }

  for (int kt = 0; kt < 32; ++kt) {
    __syncthreads();  // previous iteration's LDS reads complete
    // stage K row-major + V transposed, both swizzled
#pragma unroll
    for (int r = 0; r < 2; ++r) {
      int idx = r * 256 + t;
      int kr = idx >> 3, ch = idx & 7;
      size_t grow = (size_t)(b * S_ + kt * 64 + kr);
      u16x8 kv = *(const u16x8*)(QKV + grow * N3_ + H_ + h * HD_ + ch * 8);
      *(u16x8*)((char*)k_lds + kr * 128 + ((ch * 16) ^ ((kr & 7) << 4))) = kv;
      u16x8 vv = *(const u16x8*)(QKV + grow * N3_ + 2 * H_ + h * HD_ + ch * 8);
#pragma unroll
      for (int j = 0; j < 8; j++) {
        int d = ch * 8 + j;
        vt_lds[d * 64 + (kr ^ ((d & 7) << 3))] = (unsigned short)vv[j];
      }
    }
    __syncthreads();

    // S = Q K^T  (4 col-tiles of 16, k-dim 64 in 2 chunks)
    f32x4 sacc[4];
    for (int nt = 0; nt < 4; nt++)
      for (int r = 0; r < 4; r++) sacc[nt][r] = 0.f;
#pragma unroll
    for (int nt = 0; nt < 4; nt++) {
#pragma unroll
      for (int kb = 0; kb < 2; kb++) {
        int kr = nt * 16 + lr;
        bf16x8 kf = *(const bf16x8*)((char*)k_lds + kr * 128 +
                                     ((kb * 64 + lh * 16) ^ ((kr & 7) << 4)));
        sacc[nt] = __builtin_amdgcn_mfma_f32_16x16x32_bf16(qf[kb], kf, sacc[nt], 0, 0, 0);
      }
    }

    // online softmax (rows q = lh*4+rg; reduce over lanes lr=0..15)
    float mnew[4], alpha[4], psum[4];
#pragma unroll
    for (int rg = 0; rg < 4; rg++) {
      float mx = fmaxf(fmaxf(sacc[0][rg], sacc[1][rg]),
                       fmaxf(sacc[2][rg], sacc[3][rg])) * scale;
#pragma unroll
      for (int off = 1; off < 16; off <<= 1)
        mx = fmaxf(mx, __shfl_xor(mx, off, 64));
      float mn = fmaxf(mrun[rg], mx);
      mnew[rg] = mn;
      alpha[rg] = __expf(mrun[rg] - mn);
      mrun[rg] = mn;
      psum[rg] = 0.f;
    }
#pragma unroll
    for (int nt = 0; nt < 4; nt++)
#pragma unroll
      for (int rg = 0; rg < 4; rg++) {
        float p = __expf(sacc[nt][rg] * scale - mnew[rg]);
        psum[rg] += p;
        int q = lh * 4 + rg;
        p_lds[w][q * 64 + ((nt * 16 + lr) ^ ((q & 7) << 3))] = f2bf(p);
      }
#pragma unroll
    for (int rg = 0; rg < 4; rg++) {
      float ps = psum[rg];
#pragma unroll
      for (int off = 1; off < 16; off <<= 1)
        ps += __shfl_xor(ps, off, 64);
      lsum[rg] = lsum[rg] * alpha[rg] + ps;
    }
#pragma unroll
    for (int dt = 0; dt < 4; dt++)
#pragma unroll
      for (int rg = 0; rg < 4; rg++) o[dt][rg] *= alpha[rg];
    __syncthreads();  // p_lds writes visible (and drained) before reads

    // O += P V   (A-frag = P rows q, B-frag = V^T rows d)
#pragma unroll
    for (int kb = 0; kb < 2; kb++) {
      bf16x8 pa = *(const bf16x8*)((char*)&p_lds[w][0] + lr * 128 +
                                   ((kb * 64 + lh * 16) ^ ((lr & 7) << 4)));
#pragma unroll
      for (int dt = 0; dt < 4; dt++) {
        int d = dt * 16 + lr;
        bf16x8 vb = *(const bf16x8*)((char*)vt_lds + d * 128 +
                                     ((kb * 64 + lh * 16) ^ ((d & 7) << 4)));
        o[dt] = __builtin_amdgcn_mfma_f32_16x16x32_bf16(pa, vb, o[dt], 0, 0, 0);
      }
    }
  }

  // epilogue: divide by row sums, write fp32
#pragma unroll
  for (int dt = 0; dt < 4; dt++)
#pragma unroll
    for (int rg = 0; rg < 4; rg++) {
      int qrow = qbase + lh * 4 + rg;
      out[(size_t)(b * S_ + qrow) * H_ + h * HD_ + dt * 16 + lr] =
          o[dt][rg] / lsum[rg];
    }
}

extern "C" void kernel_launch(void* const* d_in, const int* in_sizes, int n_in,
                              void* d_out, int out_size, void* d_ws, size_t ws_size,
                              hipStream_t stream) {
  const float* emb = (const float*)d_in[0];
  const float* wqkv = (const float*)d_in[1];
  float* out = (float*)d_out;

  // workspace layout (needs ~70 MB):
  //   abf [8192][1024] bf16, wtb [3072][1024] bf16, qkv [8192][3072] bf16
  unsigned short* abf = (unsigned short*)d_ws;
  unsigned short* wtb = abf + (size_t)M_ * H_;
  unsigned short* qkv = wtb + (size_t)N3_ * H_;

  cvt_emb_kernel<<<dim3(2048), dim3(256), 0, stream>>>(emb, abf, (M_ * H_) / 4);
  cvt_w_kernel<<<dim3(2048), dim3(256), 0, stream>>>(wqkv, wtb);
  qkv_gemm_kernel<<<dim3(N3_ / 128, M_ / 128), dim3(256), 0, stream>>>(abf, wtb, qkv);
  attn_kernel<<<dim3(S_ / 64, NH_, B_), dim3(256), 0, stream>>>(qkv, out);
}

// Round 2
// 293.222 us; speedup vs baseline: 1.6548x; 1.6548x over previous
//
#include <hip/hip_runtime.h>
#include <hip/hip_bf16.h>

// ---------------------------------------------------------------------------
// MHSelfAttention: out = softmax((X Wq)(X Wk)^T / sqrt(1024)) (X Wv), 16 heads
// X: [4,2048,1024] fp32, W: [1024,3072] fp32, out: [4,2048,1024] fp32
// bf16 MFMA everywhere, fp32 accumulate + fp32 online softmax.
// Round 2: swapped QK^T (P stays in registers), pre-transposed V, LDS-tiled
// transposes for weight-cvt and V — kills the 5.9e7 bank-conflict cycles.
// ---------------------------------------------------------------------------

typedef __attribute__((ext_vector_type(8))) __bf16 bf16x8;
typedef __attribute__((ext_vector_type(8))) unsigned short u16x8;
typedef __attribute__((ext_vector_type(4))) unsigned short u16x4;
typedef __attribute__((ext_vector_type(4))) float f32x4;

#define B_  4
#define S_  2048
#define H_  1024
#define NH_ 16
#define HD_ 64
#define N3_ 3072
#define M_  (B_*S_)   // 8192

static __device__ __forceinline__ unsigned short f2bf(float f) {
  __bf16 h = (__bf16)f;
  return __builtin_bit_cast(unsigned short, h);
}

// ---- kernel 1: embeddings fp32 -> bf16 ------------------------------------
__global__ __launch_bounds__(256) void cvt_emb_kernel(
    const float* __restrict__ in, unsigned short* __restrict__ out, int n4) {
  int i = blockIdx.x * blockDim.x + threadIdx.x;
  int stride = gridDim.x * blockDim.x;
  const float4* in4 = (const float4*)in;
  for (; i < n4; i += stride) {
    float4 v = in4[i];
    ushort4 o;
    o.x = f2bf(v.x); o.y = f2bf(v.y); o.z = f2bf(v.z); o.w = f2bf(v.w);
    ((ushort4*)out)[i] = o;
  }
}

// ---- kernel 2: w fp32 [1024][3072] -> bf16 [3072][1024], LDS-tiled --------
__global__ __launch_bounds__(256) void cvt_w_kernel(
    const float* __restrict__ in, unsigned short* __restrict__ out) {
  __shared__ __align__(16) unsigned short tile[64 * 64];
  const int t = threadIdx.x;
  const int n0 = blockIdx.x * 64;   // 48 tiles over 3072
  const int k0 = blockIdx.y * 64;   // 16 tiles over 1024
#pragma unroll
  for (int it = 0; it < 4; ++it) {
    int c = it * 256 + t;          // 1024 float4 chunks
    int row = c >> 4;              // k-local
    int a = c & 15;                // n float4-chunk
    float4 v = *(const float4*)(in + (size_t)(k0 + row) * N3_ + n0 + a * 4);
    u16x4 o;
    o[0] = f2bf(v.x); o[1] = f2bf(v.y); o[2] = f2bf(v.z); o[3] = f2bf(v.w);
    int swz = (((row & 7) ^ ((row >> 3) & 7)) << 4);
    *(u16x4*)((char*)tile + row * 128 + ((a * 8) ^ swz)) = o;
  }
  __syncthreads();
#pragma unroll
  for (int it = 0; it < 2; ++it) {
    int c = it * 256 + t;          // 512 out-chunks of 8
    int n = c >> 3;
    int a = c & 7;
    u16x8 o;
#pragma unroll
    for (int j = 0; j < 8; ++j) {
      int k = a * 8 + j;
      int swz = (((k & 7) ^ ((k >> 3) & 7)) << 4);
      o[j] = *(const unsigned short*)((char*)tile + k * 128 + ((2 * n) ^ swz));
    }
    *(u16x8*)(out + (size_t)(n0 + n) * H_ + k0 + a * 8) = o;
  }
}

// ---- kernel 3: QKV GEMM (unchanged, proven) -------------------------------
__global__ __launch_bounds__(256) void qkv_gemm_kernel(
    const unsigned short* __restrict__ A,
    const unsigned short* __restrict__ BT,
    unsigned short* __restrict__ C) {
  __shared__ __align__(16) unsigned short a_lds[128 * 64];
  __shared__ __align__(16) unsigned short b_lds[128 * 64];
  const int t = threadIdx.x;
  const int lane = t & 63;
  const int w = t >> 6;
  const int wm = w >> 1, wn = w & 1;
  const int m0 = blockIdx.y * 128;
  const int n0 = blockIdx.x * 128;
  const int lr = lane & 15;
  const int lh = lane >> 4;

  f32x4 acc[4][4];
  for (int i = 0; i < 4; i++)
    for (int j = 0; j < 4; j++)
      for (int r = 0; r < 4; r++) acc[i][j][r] = 0.f;

  for (int kt = 0; kt < 16; ++kt) {
    __syncthreads();
#pragma unroll
    for (int r = 0; r < 4; ++r) {
      int idx = r * 256 + t;
      int row = idx >> 3, ch = idx & 7;
      int sw = (ch * 16) ^ ((row & 7) << 4);
      u16x8 av = *(const u16x8*)(A + (size_t)(m0 + row) * H_ + kt * 64 + ch * 8);
      *(u16x8*)((char*)a_lds + row * 128 + sw) = av;
      u16x8 bv = *(const u16x8*)(BT + (size_t)(n0 + row) * H_ + kt * 64 + ch * 8);
      *(u16x8*)((char*)b_lds + row * 128 + sw) = bv;
    }
    __syncthreads();
#pragma unroll
    for (int kb = 0; kb < 2; ++kb) {
      bf16x8 af[4], bfr[4];
#pragma unroll
      for (int mi = 0; mi < 4; mi++) {
        int row = wm * 64 + mi * 16 + lr;
        int off = (kb * 64 + lh * 16) ^ ((row & 7) << 4);
        af[mi] = *(const bf16x8*)((char*)a_lds + row * 128 + off);
      }
#pragma unroll
      for (int ni = 0; ni < 4; ni++) {
        int row = wn * 64 + ni * 16 + lr;
        int off = (kb * 64 + lh * 16) ^ ((row & 7) << 4);
        bfr[ni] = *(const bf16x8*)((char*)b_lds + row * 128 + off);
      }
#pragma unroll
      for (int mi = 0; mi < 4; mi++)
#pragma unroll
        for (int ni = 0; ni < 4; ni++)
          acc[mi][ni] = __builtin_amdgcn_mfma_f32_16x16x32_bf16(
              af[mi], bfr[ni], acc[mi][ni], 0, 0, 0);
    }
  }
#pragma unroll
  for (int mi = 0; mi < 4; mi++)
#pragma unroll
    for (int ni = 0; ni < 4; ni++)
#pragma unroll
      for (int rg = 0; rg < 4; rg++) {
        int row = m0 + wm * 64 + mi * 16 + lh * 4 + rg;
        int col = n0 + wn * 64 + ni * 16 + lr;
        C[(size_t)row * N3_ + col] = f2bf(acc[mi][ni][rg]);
      }
}

// ---- kernel 4: V transpose: qkv V-part [s][d] -> Vt [b][h][d][s] ----------
__global__ __launch_bounds__(256) void vtrans_kernel(
    const unsigned short* __restrict__ qkv, unsigned short* __restrict__ vt) {
  __shared__ __align__(16) unsigned short tile[64 * 64];
  const int t = threadIdx.x;
  const int st = blockIdx.x;   // 32 s-tiles
  const int h = blockIdx.y;
  const int b = blockIdx.z;
  const int s0 = st * 64;
#pragma unroll
  for (int it = 0; it < 2; ++it) {
    int c = it * 256 + t;        // 512 chunks of 16B
    int row = c >> 3;            // s-local
    int a = c & 7;               // d-chunk
    u16x8 v = *(const u16x8*)(qkv + (size_t)(b * S_ + s0 + row) * N3_ +
                              2 * H_ + h * HD_ + a * 8);
    int swz = (((row & 7) ^ ((row >> 3) & 7)) << 4);
    *(u16x8*)((char*)tile + row * 128 + ((a * 16) ^ swz)) = v;
  }
  __syncthreads();
#pragma unroll
  for (int it = 0; it < 2; ++it) {
    int c = it * 256 + t;
    int d = c >> 3;
    int a = c & 7;               // s-chunk
    u16x8 o;
#pragma unroll
    for (int j = 0; j < 8; ++j) {
      int r = a * 8 + j;         // s-local
      int swz = (((r & 7) ^ ((r >> 3) & 7)) << 4);
      o[j] = *(const unsigned short*)((char*)tile + r * 128 + ((2 * d) ^ swz));
    }
    *(u16x8*)(vt + ((size_t)((b * NH_ + h) * HD_) + d) * S_ + s0 + a * 8) = o;
  }
}

// ---- kernel 5: flash attention, swapped QK^T, P in registers --------------
// grid (qtile=32, head=16, batch=4), 256 thr. Wave w owns q-rows qt*64+w*16+.
// Lane (lr,lh): softmax state for q=lr; output rows q=lh*4+rg, col d=lr.
__global__ __launch_bounds__(256) void attn_kernel(
    const unsigned short* __restrict__ QKV,
    const unsigned short* __restrict__ VT,
    float* __restrict__ out) {
  __shared__ __align__(16) unsigned short k_lds[64 * 64];
  __shared__ __align__(16) unsigned short vt_lds[64 * 64];
  const int t = threadIdx.x;
  const int lane = t & 63;
  const int w = t >> 6;
  const int lr = lane & 15, lh = lane >> 4;
  const int qt = blockIdx.x;
  const int h = blockIdx.y;
  const int b = blockIdx.z;
  const int qbase = qt * 64 + w * 16;
  const float scale = 0.03125f;   // 1/sqrt(1024)

  // Q B-fragments (rows q=lr, d-slots 32*kb + lh*8 + j) — resident all kernel
  bf16x8 qf[2];
  {
    const unsigned short* qp =
        QKV + (size_t)(b * S_ + qbase + lr) * N3_ + h * HD_ + lh * 8;
    qf[0] = *(const bf16x8*)(qp);
    qf[1] = *(const bf16x8*)(qp + 32);
  }

  f32x4 o[4];
#pragma unroll
  for (int i = 0; i < 4; i++)
#pragma unroll
    for (int r = 0; r < 4; r++) o[i][r] = 0.f;
  float mrun = -1e30f, lsum = 0.f;

  const unsigned short* kbase = QKV + (size_t)(b * S_) * N3_ + H_ + h * HD_;
  const unsigned short* vbase = VT + (size_t)((b * NH_ + h) * HD_) * S_;

  for (int kt = 0; kt < 32; ++kt) {
    __syncthreads();
    // ---- stage K [64 kv][64 d] + Vt [64 d][64 s, permuted chunks] ----
#pragma unroll
    for (int it = 0; it < 2; ++it) {
      int c = it * 256 + t;
      int row = c >> 3, a = c & 7;
      u16x8 kv = *(const u16x8*)(kbase + (size_t)(kt * 64 + row) * N3_ + a * 8);
      *(u16x8*)((char*)k_lds + row * 128 + ((a * 16) ^ ((row & 7) << 4))) = kv;
      u16x8 vv = *(const u16x8*)(vbase + (size_t)row * S_ + kt * 64 + a * 8);
      // split into two 8B chunks at pi-permuted positions:
      // s0 -> p = (kb<<3)|(lhi<<1)|ti  with kb=s0>>5, lhi=(s0>>2)&3, ti=(s0>>4)&1
      int s0a = a * 8, s0b = a * 8 + 4;
      int p_lo = ((s0a >> 5) << 3) | (((s0a >> 2) & 3) << 1) | ((s0a >> 4) & 1);
      int p_hi = ((s0b >> 5) << 3) | (((s0b >> 2) & 3) << 1) | ((s0b >> 4) & 1);
      u16x4 lo = {vv[0], vv[1], vv[2], vv[3]};
      u16x4 hi = {vv[4], vv[5], vv[6], vv[7]};
      int rsw = (row & 7) << 4;
      *(u16x4*)((char*)vt_lds + row * 128 + ((p_lo * 8) ^ rsw)) = lo;
      *(u16x4*)((char*)vt_lds + row * 128 + ((p_hi * 8) ^ rsw)) = hi;
    }
    __syncthreads();

    // ---- S^T = K Q^T : sacc[nt][rg] = S[k=nt*16+lh*4+rg][q=lr]*1 ----
    f32x4 sacc[4];
#pragma unroll
    for (int nt = 0; nt < 4; nt++)
#pragma unroll
      for (int r = 0; r < 4; r++) sacc[nt][r] = 0.f;
#pragma unroll
    for (int nt = 0; nt < 4; ++nt) {
#pragma unroll
      for (int kb = 0; kb < 2; ++kb) {
        int row = nt * 16 + lr;
        bf16x8 kf = *(const bf16x8*)((char*)k_lds + row * 128 +
                                     ((64 * kb + 16 * lh) ^ ((row & 7) << 4)));
        sacc[nt] = __builtin_amdgcn_mfma_f32_16x16x32_bf16(kf, qf[kb], sacc[nt], 0, 0, 0);
      }
    }

    // ---- online softmax: row q=lr spread over lanes {lr+16*lh} ----
    float mx = -1e30f;
#pragma unroll
    for (int nt = 0; nt < 4; nt++)
#pragma unroll
      for (int rg = 0; rg < 4; rg++) mx = fmaxf(mx, sacc[nt][rg]);
    mx *= scale;
    mx = fmaxf(mx, __shfl_xor(mx, 16, 64));
    mx = fmaxf(mx, __shfl_xor(mx, 32, 64));
    float mn = fmaxf(mrun, mx);
    float alpha = __expf(mrun - mn);
    mrun = mn;

    float p[4][4];
    float ps = 0.f;
#pragma unroll
    for (int nt = 0; nt < 4; nt++)
#pragma unroll
      for (int rg = 0; rg < 4; rg++) {
        float e = __expf(sacc[nt][rg] * scale - mn);
        p[nt][rg] = e;
        ps += e;
      }
    ps += __shfl_xor(ps, 16, 64);
    ps += __shfl_xor(ps, 32, 64);
    lsum = lsum * alpha + ps;

    // pack PV A-frag: slot (kb,j) <-> p[2*kb + (j>>2)][j&3]  (lane-local!)
    bf16x8 pa[2];
#pragma unroll
    for (int kb = 0; kb < 2; ++kb)
#pragma unroll
      for (int j = 0; j < 8; ++j)
        pa[kb][j] = (__bf16)p[2 * kb + (j >> 2)][j & 3];

    // rescale O by alpha of its q-row (q = lh*4+rg, held by lane lh*4+rg)
    float al[4];
#pragma unroll
    for (int rg = 0; rg < 4; ++rg) al[rg] = __shfl(alpha, lh * 4 + rg, 64);
#pragma unroll
    for (int dt = 0; dt < 4; ++dt)
#pragma unroll
      for (int rg = 0; rg < 4; ++rg) o[dt][rg] *= al[rg];

    // ---- O += P V ----
#pragma unroll
    for (int kb = 0; kb < 2; ++kb) {
#pragma unroll
      for (int dt = 0; dt < 4; ++dt) {
        int row = dt * 16 + lr;
        bf16x8 vb = *(const bf16x8*)((char*)vt_lds + row * 128 +
                                     ((64 * kb + 16 * lh) ^ ((row & 7) << 4)));
        o[dt] = __builtin_amdgcn_mfma_f32_16x16x32_bf16(pa[kb], vb, o[dt], 0, 0, 0);
      }
    }
  }

  // ---- epilogue: divide by row-sum of the OUTPUT row q=lh*4+rg ----
  float ls[4];
#pragma unroll
  for (int rg = 0; rg < 4; ++rg) ls[rg] = __shfl(lsum, lh * 4 + rg, 64);
#pragma unroll
  for (int dt = 0; dt < 4; ++dt)
#pragma unroll
    for (int rg = 0; rg < 4; ++rg) {
      int qrow = qbase + lh * 4 + rg;
      out[(size_t)(b * S_ + qrow) * H_ + h * HD_ + dt * 16 + lr] =
          o[dt][rg] / ls[rg];
    }
}

extern "C" void kernel_launch(void* const* d_in, const int* in_sizes, int n_in,
                              void* d_out, int out_size, void* d_ws, size_t ws_size,
                              hipStream_t stream) {
  const float* emb = (const float*)d_in[0];
  const float* wqkv = (const float*)d_in[1];
  float* out = (float*)d_out;

  // ws layout (70 MB): abf 16MB | wtb 6MB | qkv 48MB.  Vt aliases abf
  // (abf is dead after the GEMM; single-stream ordering makes this safe).
  unsigned short* abf = (unsigned short*)d_ws;
  unsigned short* wtb = abf + (size_t)M_ * H_;
  unsigned short* qkv = wtb + (size_t)N3_ * H_;
  unsigned short* vt = abf;

  cvt_emb_kernel<<<dim3(2048), dim3(256), 0, stream>>>(emb, abf, (M_ * H_) / 4);
  cvt_w_kernel<<<dim3(48, 16), dim3(256), 0, stream>>>(wqkv, wtb);
  qkv_gemm_kernel<<<dim3(N3_ / 128, M_ / 128), dim3(256), 0, stream>>>(abf, wtb, qkv);
  vtrans_kernel<<<dim3(32, 16, 4), dim3(256), 0, stream>>>(qkv, vt);
  attn_kernel<<<dim3(32, 16, 4), dim3(256), 0, stream>>>(qkv, vt, out);
}

// Round 3
// 248.410 us; speedup vs baseline: 1.9533x; 1.1804x over previous
//
#include <hip/hip_runtime.h>
#include <hip/hip_bf16.h>

// ---------------------------------------------------------------------------
// MHSelfAttention: out = softmax((X Wq)(X Wk)^T / sqrt(1024)) (X Wv), 16 heads
// Round 3: GEMM staged via global_load_lds (pre-swizzled source, swizzled
// reads); Q pre-scaled by log2e/32 in GEMM epilogue; attn reworked to
// 32 q-rows/wave with defer-max softmax, lsum-via-ones-MFMA, async staging.
// ---------------------------------------------------------------------------

typedef __attribute__((ext_vector_type(8))) __bf16 bf16x8;
typedef __attribute__((ext_vector_type(8))) unsigned short u16x8;
typedef __attribute__((ext_vector_type(4))) unsigned short u16x4;
typedef __attribute__((ext_vector_type(4))) float f32x4;

#define B_  4
#define S_  2048
#define H_  1024
#define NH_ 16
#define HD_ 64
#define N3_ 3072
#define M_  (B_*S_)   // 8192

static __device__ __forceinline__ unsigned short f2bf(float f) {
  __bf16 h = (__bf16)f;
  return __builtin_bit_cast(unsigned short, h);
}

static __device__ __forceinline__ float exp2_fast(float x) {
  float r; asm("v_exp_f32 %0, %1" : "=v"(r) : "v"(x)); return r;
}

// async global->LDS, 16B per lane; LDS dst must be wave-uniform base
static __device__ __forceinline__ void gload_lds16(const unsigned short* g,
                                                   unsigned short* l) {
  __builtin_amdgcn_global_load_lds(
      (const __attribute__((address_space(1))) unsigned int*)g,
      (__attribute__((address_space(3))) unsigned int*)l, 16, 0, 0);
}

// ---- kernel 1: embeddings fp32 -> bf16 ------------------------------------
__global__ __launch_bounds__(256) void cvt_emb_kernel(
    const float* __restrict__ in, unsigned short* __restrict__ out, int n4) {
  int i = blockIdx.x * blockDim.x + threadIdx.x;
  int stride = gridDim.x * blockDim.x;
  const float4* in4 = (const float4*)in;
  for (; i < n4; i += stride) {
    float4 v = in4[i];
    ushort4 o;
    o.x = f2bf(v.x); o.y = f2bf(v.y); o.z = f2bf(v.z); o.w = f2bf(v.w);
    ((ushort4*)out)[i] = o;
  }
}

// ---- kernel 2: w fp32 [1024][3072] -> bf16 [3072][1024], LDS-tiled --------
__global__ __launch_bounds__(256) void cvt_w_kernel(
    const float* __restrict__ in, unsigned short* __restrict__ out) {
  __shared__ __align__(16) unsigned short tile[64 * 64];
  const int t = threadIdx.x;
  const int n0 = blockIdx.x * 64;
  const int k0 = blockIdx.y * 64;
#pragma unroll
  for (int it = 0; it < 4; ++it) {
    int c = it * 256 + t;
    int row = c >> 4;
    int a = c & 15;
    float4 v = *(const float4*)(in + (size_t)(k0 + row) * N3_ + n0 + a * 4);
    u16x4 o;
    o[0] = f2bf(v.x); o[1] = f2bf(v.y); o[2] = f2bf(v.z); o[3] = f2bf(v.w);
    int swz = (((row & 7) ^ ((row >> 3) & 7)) << 4);
    *(u16x4*)((char*)tile + row * 128 + ((a * 8) ^ swz)) = o;
  }
  __syncthreads();
#pragma unroll
  for (int it = 0; it < 2; ++it) {
    int c = it * 256 + t;
    int n = c >> 3;
    int a = c & 7;
    u16x8 o;
#pragma unroll
    for (int j = 0; j < 8; ++j) {
      int k = a * 8 + j;
      int swz = (((k & 7) ^ ((k >> 3) & 7)) << 4);
      o[j] = *(const unsigned short*)((char*)tile + k * 128 + ((2 * n) ^ swz));
    }
    *(u16x8*)(out + (size_t)(n0 + n) * H_ + k0 + a * 8) = o;
  }
}

// ---- kernel 3: QKV GEMM, global_load_lds staging --------------------------
// 128x128 tile, BK=64, 4 waves (2x2). LDS linear dest + inverse-swizzled
// global source; frag reads use the swizzle (conflict-free, proven r2).
// Q columns (n < 1024) pre-scaled by log2e/32 for the attn exp2 path.
__global__ __launch_bounds__(256, 3) void qkv_gemm_kernel(
    const unsigned short* __restrict__ A,
    const unsigned short* __restrict__ BT,
    unsigned short* __restrict__ C) {
  __shared__ __align__(16) unsigned short a_lds[128 * 64];
  __shared__ __align__(16) unsigned short b_lds[128 * 64];
  const int t = threadIdx.x;
  const int lane = t & 63;
  const int w = t >> 6;
  const int wm = w >> 1, wn = w & 1;
  const int m0 = blockIdx.y * 128;
  const int n0 = blockIdx.x * 128;
  const int lr = lane & 15;
  const int lh = lane >> 4;
  const int sr8 = lane >> 3;          // row-within-8 staged by this lane
  const int sch = (lane & 7) ^ sr8;   // pre-swizzled source chunk

  f32x4 acc[4][4];
#pragma unroll
  for (int i = 0; i < 4; i++)
#pragma unroll
    for (int j = 0; j < 4; j++)
#pragma unroll
      for (int r = 0; r < 4; r++) acc[i][j][r] = 0.f;

  const unsigned short* Abase = A + (size_t)(m0 + w * 32 + sr8) * H_ + sch * 8;
  const unsigned short* Bbase = BT + (size_t)(n0 + w * 32 + sr8) * H_ + sch * 8;

  for (int kt = 0; kt < 16; ++kt) {
    __syncthreads();
#pragma unroll
    for (int i = 0; i < 4; ++i) {
      gload_lds16(Abase + (size_t)(i * 8) * H_ + kt * 64,
                  &a_lds[(w * 32 + i * 8) * 64]);
      gload_lds16(Bbase + (size_t)(i * 8) * H_ + kt * 64,
                  &b_lds[(w * 32 + i * 8) * 64]);
    }
    __syncthreads();
#pragma unroll
    for (int kb = 0; kb < 2; ++kb) {
      bf16x8 af[4], bfr[4];
#pragma unroll
      for (int mi = 0; mi < 4; mi++) {
        int row = wm * 64 + mi * 16 + lr;
        int off = (kb * 64 + lh * 16) ^ ((row & 7) << 4);
        af[mi] = *(const bf16x8*)((char*)a_lds + row * 128 + off);
      }
#pragma unroll
      for (int ni = 0; ni < 4; ni++) {
        int row = wn * 64 + ni * 16 + lr;
        int off = (kb * 64 + lh * 16) ^ ((row & 7) << 4);
        bfr[ni] = *(const bf16x8*)((char*)b_lds + row * 128 + off);
      }
#pragma unroll
      for (int mi = 0; mi < 4; mi++)
#pragma unroll
        for (int ni = 0; ni < 4; ni++)
          acc[mi][ni] = __builtin_amdgcn_mfma_f32_16x16x32_bf16(
              af[mi], bfr[ni], acc[mi][ni], 0, 0, 0);
    }
  }
  const float mult = (n0 < H_) ? 0.045084220027780106f : 1.0f;  // log2e/32
#pragma unroll
  for (int mi = 0; mi < 4; mi++)
#pragma unroll
    for (int ni = 0; ni < 4; ni++)
#pragma unroll
      for (int rg = 0; rg < 4; rg++) {
        int row = m0 + wm * 64 + mi * 16 + lh * 4 + rg;
        int col = n0 + wn * 64 + ni * 16 + lr;
        C[(size_t)row * N3_ + col] = f2bf(acc[mi][ni][rg] * mult);
      }
}

// ---- kernel 4: V transpose -> vt [b][h][d][s], pi-permuted 8B slots -------
// Slot p = (kb<<3)|(lhi<<1)|ti holds s-local kb*32+ti*16+lhi*4+{0..3} so attn
// can stage V with plain vector writes and PV frag reads get the QK^T-output
// k-ordering directly.
__global__ __launch_bounds__(256) void vtrans_kernel(
    const unsigned short* __restrict__ qkv, unsigned short* __restrict__ vt) {
  __shared__ __align__(16) unsigned short tile[64 * 64];
  const int t = threadIdx.x;
  const int st = blockIdx.x;
  const int h = blockIdx.y;
  const int b = blockIdx.z;
  const int s0 = st * 64;
#pragma unroll
  for (int it = 0; it < 2; ++it) {
    int c = it * 256 + t;
    int row = c >> 3;            // s-local
    int a = c & 7;               // d-chunk
    u16x8 v = *(const u16x8*)(qkv + (size_t)(b * S_ + s0 + row) * N3_ +
                              2 * H_ + h * HD_ + a * 8);
    int swz = (((row & 7) ^ ((row >> 3) & 7)) << 4);
    *(u16x8*)((char*)tile + row * 128 + ((a * 16) ^ swz)) = v;
  }
  __syncthreads();
#pragma unroll
  for (int it = 0; it < 2; ++it) {
    int c = it * 256 + t;
    int d = c >> 3;
    int a = c & 7;               // s-chunk (8 values)
    u16x8 o;
#pragma unroll
    for (int j = 0; j < 8; ++j) {
      int r = a * 8 + j;
      int swz = (((r & 7) ^ ((r >> 3) & 7)) << 4);
      o[j] = *(const unsigned short*)((char*)tile + r * 128 + ((2 * d) ^ swz));
    }
    int s0a = a * 8, s0b = a * 8 + 4;
    int p_lo = ((s0a >> 5) << 3) | (((s0a >> 2) & 3) << 1) | ((s0a >> 4) & 1);
    int p_hi = ((s0b >> 5) << 3) | (((s0b >> 2) & 3) << 1) | ((s0b >> 4) & 1);
    unsigned short* dst =
        vt + ((size_t)((b * NH_ + h) * HD_) + d) * S_ + s0;
    u16x4 lo = {o[0], o[1], o[2], o[3]};
    u16x4 hi = {o[4], o[5], o[6], o[7]};
    *(u16x4*)(dst + p_lo * 4) = lo;
    *(u16x4*)(dst + p_hi * 4) = hi;
  }
}

// ---- kernel 5: flash attention, 32 q-rows/wave ----------------------------
// grid (16, 16, 4), 256 thr. Wave owns q-rows qw..qw+31 (2 subtiles of 16).
// Defer-max softmax (base-2, thr 8); lsum via ones-column MFMA; K/V loads
// issued one tile ahead (T14), ds_write after barrier.
__global__ __launch_bounds__(256, 3) void attn_kernel(
    const unsigned short* __restrict__ QKV,
    const unsigned short* __restrict__ VT,
    float* __restrict__ out) {
  __shared__ __align__(16) unsigned short k_lds[64 * 64];
  __shared__ __align__(16) unsigned short vt_lds[64 * 64];
  const int t = threadIdx.x;
  const int lane = t & 63;
  const int w = t >> 6;
  const int lr = lane & 15, lh = lane >> 4;
  const int h = blockIdx.y;
  const int b = blockIdx.z;
  const int qw = blockIdx.x * 128 + w * 32;

  // Q fragments (already scaled by log2e/32)
  bf16x8 qf[2][2];
#pragma unroll
  for (int qi = 0; qi < 2; ++qi) {
    const unsigned short* qp =
        QKV + (size_t)(b * S_ + qw + qi * 16 + lr) * N3_ + h * HD_ + lh * 8;
    qf[qi][0] = *(const bf16x8*)qp;
    qf[qi][1] = *(const bf16x8*)(qp + 32);
  }

  // ones B-frag: V-row d=0 equal to 1 -> PV also accumulates row-sum at d=0
  bf16x8 ones;
#pragma unroll
  for (int j = 0; j < 8; ++j) ones[j] = (lr == 0) ? (__bf16)1.0f : (__bf16)0.0f;

  f32x4 o[2][4], o5[2];
#pragma unroll
  for (int qi = 0; qi < 2; ++qi) {
#pragma unroll
    for (int i = 0; i < 4; i++)
#pragma unroll
      for (int r = 0; r < 4; r++) o[qi][i][r] = 0.f;
#pragma unroll
    for (int r = 0; r < 4; r++) o5[qi][r] = 0.f;
  }
  float mrun[2] = {-3e38f, -3e38f};

  // staging: thread covers chunks t and t+256 of each 64x64 tile
  const int row0 = t >> 3, a0 = t & 7;
  const int row1 = (256 + t) >> 3, a1 = t & 7;
  const int dst0 = row0 * 128 + ((a0 * 16) ^ ((row0 & 7) << 4));
  const int dst1 = row1 * 128 + ((a1 * 16) ^ ((row1 & 7) << 4));
  const unsigned short* kbase = QKV + (size_t)(b * S_) * N3_ + H_ + h * HD_;
  const unsigned short* vbase = VT + (size_t)((b * NH_ + h) * HD_) * S_;

  u16x8 gk0 = *(const u16x8*)(kbase + (size_t)row0 * N3_ + a0 * 8);
  u16x8 gk1 = *(const u16x8*)(kbase + (size_t)row1 * N3_ + a1 * 8);
  u16x8 gv0 = *(const u16x8*)(vbase + (size_t)row0 * S_ + a0 * 8);
  u16x8 gv1 = *(const u16x8*)(vbase + (size_t)row1 * S_ + a1 * 8);

  for (int kt = 0; kt < 32; ++kt) {
    __syncthreads();                       // prior LDS reads done
    *(u16x8*)((char*)k_lds + dst0) = gk0;
    *(u16x8*)((char*)k_lds + dst1) = gk1;
    *(u16x8*)((char*)vt_lds + dst0) = gv0;
    *(u16x8*)((char*)vt_lds + dst1) = gv1;
    __syncthreads();                       // tile ready

    // issue next-tile loads now; latency hides under compute (T14)
    {
      int ktn = (kt + 1) & 31;
      const unsigned short* kp = kbase + (size_t)(ktn * 64) * N3_;
      const unsigned short* vp = vbase + ktn * 64;
      gk0 = *(const u16x8*)(kp + (size_t)row0 * N3_ + a0 * 8);
      gk1 = *(const u16x8*)(kp + (size_t)row1 * N3_ + a1 * 8);
      gv0 = *(const u16x8*)(vp + (size_t)row0 * S_ + a0 * 8);
      gv1 = *(const u16x8*)(vp + (size_t)row1 * S_ + a1 * 8);
    }

    // ---- S^T = K Q^T (base-2-scaled) ----
    f32x4 sacc[2][4];
#pragma unroll
    for (int qi = 0; qi < 2; ++qi)
#pragma unroll
      for (int nt = 0; nt < 4; nt++)
#pragma unroll
        for (int r = 0; r < 4; r++) sacc[qi][nt][r] = 0.f;
#pragma unroll
    for (int nt = 0; nt < 4; ++nt) {
#pragma unroll
      for (int kb = 0; kb < 2; ++kb) {
        int row = nt * 16 + lr;
        bf16x8 kf = *(const bf16x8*)((char*)k_lds + row * 128 +
                                     ((64 * kb + 16 * lh) ^ ((row & 7) << 4)));
        sacc[0][nt] = __builtin_amdgcn_mfma_f32_16x16x32_bf16(kf, qf[0][kb], sacc[0][nt], 0, 0, 0);
        sacc[1][nt] = __builtin_amdgcn_mfma_f32_16x16x32_bf16(kf, qf[1][kb], sacc[1][nt], 0, 0, 0);
      }
    }

    // ---- tile max per q-subtile (row q=lr, spread over lh groups) ----
    float mx[2];
#pragma unroll
    for (int qi = 0; qi < 2; ++qi) {
      float m = fmaxf(fmaxf(fmaxf(sacc[qi][0][0], sacc[qi][0][1]),
                            fmaxf(sacc[qi][0][2], sacc[qi][0][3])),
                      fmaxf(fmaxf(sacc[qi][1][0], sacc[qi][1][1]),
                            fmaxf(sacc[qi][1][2], sacc[qi][1][3])));
      float m2 = fmaxf(fmaxf(fmaxf(sacc[qi][2][0], sacc[qi][2][1]),
                             fmaxf(sacc[qi][2][2], sacc[qi][2][3])),
                       fmaxf(fmaxf(sacc[qi][3][0], sacc[qi][3][1]),
                             fmaxf(sacc[qi][3][2], sacc[qi][3][3])));
      m = fmaxf(m, m2);
      m = fmaxf(m, __shfl_xor(m, 16, 64));
      m = fmaxf(m, __shfl_xor(m, 32, 64));
      mx[qi] = m;
    }

    // ---- defer-max: rescale only when a row max grew past threshold ----
    bool ok = (mx[0] <= mrun[0] + 8.0f) && (mx[1] <= mrun[1] + 8.0f);
    if (!__all(ok)) {
#pragma unroll
      for (int qi = 0; qi < 2; ++qi) {
        float mn = fmaxf(mrun[qi], mx[qi]);
        float alpha = exp2_fast(mrun[qi] - mn);
        mrun[qi] = mn;
        float al[4];
#pragma unroll
        for (int rg = 0; rg < 4; ++rg) al[rg] = __shfl(alpha, lh * 4 + rg, 64);
#pragma unroll
        for (int dt = 0; dt < 4; ++dt)
#pragma unroll
          for (int rg = 0; rg < 4; ++rg) o[qi][dt][rg] *= al[rg];
#pragma unroll
        for (int rg = 0; rg < 4; ++rg) o5[qi][rg] *= al[rg];
      }
    }

    // ---- P = 2^(S - m), packed straight into PV A-frags (lane-local) ----
    bf16x8 pa[2][2];
#pragma unroll
    for (int qi = 0; qi < 2; ++qi)
#pragma unroll
      for (int kb = 0; kb < 2; ++kb)
#pragma unroll
        for (int j = 0; j < 8; ++j)
          pa[qi][kb][j] =
              (__bf16)exp2_fast(sacc[qi][2 * kb + (j >> 2)][j & 3] - mrun[qi]);

    // ---- O += P V ; o5 += P ones ----
#pragma unroll
    for (int kb = 0; kb < 2; ++kb) {
#pragma unroll
      for (int dt = 0; dt < 4; ++dt) {
        int row = dt * 16 + lr;
        bf16x8 vb = *(const bf16x8*)((char*)vt_lds + row * 128 +
                                     ((64 * kb + 16 * lh) ^ ((row & 7) << 4)));
        o[0][dt] = __builtin_amdgcn_mfma_f32_16x16x32_bf16(pa[0][kb], vb, o[0][dt], 0, 0, 0);
        o[1][dt] = __builtin_amdgcn_mfma_f32_16x16x32_bf16(pa[1][kb], vb, o[1][dt], 0, 0, 0);
      }
      o5[0] = __builtin_amdgcn_mfma_f32_16x16x32_bf16(pa[0][kb], ones, o5[0], 0, 0, 0);
      o5[1] = __builtin_amdgcn_mfma_f32_16x16x32_bf16(pa[1][kb], ones, o5[1], 0, 0, 0);
    }
  }

  // ---- epilogue ----
#pragma unroll
  for (int qi = 0; qi < 2; ++qi) {
    float inv[4];
#pragma unroll
    for (int rg = 0; rg < 4; ++rg) {
      float ls = __shfl(o5[qi][rg], lh * 16, 64);  // D[row=q][col=0]
      inv[rg] = 1.0f / ls;
    }
#pragma unroll
    for (int dt = 0; dt < 4; ++dt)
#pragma unroll
      for (int rg = 0; rg < 4; ++rg) {
        int qrow = qw + qi * 16 + lh * 4 + rg;
        out[(size_t)(b * S_ + qrow) * H_ + h * HD_ + dt * 16 + lr] =
            o[qi][dt][rg] * inv[rg];
      }
  }
}

extern "C" void kernel_launch(void* const* d_in, const int* in_sizes, int n_in,
                              void* d_out, int out_size, void* d_ws, size_t ws_size,
                              hipStream_t stream) {
  const float* emb = (const float*)d_in[0];
  const float* wqkv = (const float*)d_in[1];
  float* out = (float*)d_out;

  // ws layout (70 MB): abf 16MB | wtb 6MB | qkv 48MB. vt aliases abf.
  unsigned short* abf = (unsigned short*)d_ws;
  unsigned short* wtb = abf + (size_t)M_ * H_;
  unsigned short* qkv = wtb + (size_t)N3_ * H_;
  unsigned short* vt = abf;

  cvt_emb_kernel<<<dim3(2048), dim3(256), 0, stream>>>(emb, abf, (M_ * H_) / 4);
  cvt_w_kernel<<<dim3(48, 16), dim3(256), 0, stream>>>(wqkv, wtb);
  qkv_gemm_kernel<<<dim3(N3_ / 128, M_ / 128), dim3(256), 0, stream>>>(abf, wtb, qkv);
  vtrans_kernel<<<dim3(32, 16, 4), dim3(256), 0, stream>>>(qkv, vt);
  attn_kernel<<<dim3(16, 16, 4), dim3(256), 0, stream>>>(qkv, vt, out);
}